// Round 1
// baseline (10967.889 us; speedup 1.0000x reference)
//
#include <hip/hip_runtime.h>
#include <hip/hip_bf16.h>

// LSTM encoder: B=64, T=2048, D=256, H=512.
// Persistent-RNN: 128 wgs (1/CU via ~148KB LDS), each owns a [768 x 64] bf16
// slice of [U;W] in LDS. Changes vs prior version:
//  - Barrier: per-WAVE epoch flags (128 u32 per tile, store+poll, NO atomic
//    RMW, no (D) barrier). Each wave drains its own h-stores then stores its
//    flag; wave0 polls all 128 flags of the tile.
//  - Split GEMM: acc_x (W·x, 8 MFMAs) computed at step start overlapped with
//    the h global-load latency; x_{t+1} staged by waves 1-3 during the poll.
//    Only 16 U·h MFMAs remain on the post-barrier critical path.
//  - zh/zx LDS tiles XOR-swizzled (byte ^= (row&7)<<4): conflict-free
//    ds_read_b128 a-frags via two per-lane base pointers (zero per-read VALU).
// Ordering: h publish stores are sc1 (agent-scope write-through); each wave
// drains vmcnt before storing its flag; consumers' relaxed sc1 loads then
// read the coherence point -> no stale data. Same pattern as prior version.

#define B_   64
#define T_   2048
#define D_   256
#define H_   512
#define G4   2048          // 4H
#define KTOT 768           // H + D
#define KK   24            // KTOT / 32
#define TILES 4            // B/16
#define SLICES 32          // H/16
#define UWP  40            // UWL row length (bf16 elems), 32 + 8 pad
#define BSTR (64 * UWP)    // UWL kk-slab stride in elems

#define OFF_UWL 0
#define SZ_UWL  (KK * 64 * UWP * 2)          // 122880
#define OFF_ZH  (OFF_UWL + SZ_UWL)           // 122880
#define SZ_ZH   (16 * 512 * 2)               // 16384 (h part, swizzled)
#define OFF_ZX  (OFF_ZH + SZ_ZH)             // 139264
#define SZ_ZX   (16 * 256 * 2)               // 8192  (x part, swizzled)
#define OFF_GT  (OFF_ZX + SZ_ZX)             // 147456
#define SZ_GT   (4 * 16 * 17 * 4)            // 4352
#define OFF_BS  (OFF_GT + SZ_GT)             // 151808
#define SZ_BS   (64 * 4)                     // 256
#define SMEM_BYTES (OFF_BS + SZ_BS)          // 152064 < 160 KiB

typedef __attribute__((ext_vector_type(8))) short v8s;
typedef __attribute__((ext_vector_type(4))) float v4f;

__device__ __forceinline__ unsigned short f2bf(float f) {
    unsigned u = __builtin_bit_cast(unsigned, f);
    u = (u + 0x7FFFu + ((u >> 16) & 1u)) >> 16;   // RTNE
    return (unsigned short)u;
}
__device__ __forceinline__ unsigned long long pack4(float4 v) {
    return (unsigned long long)((unsigned)f2bf(v.x) | ((unsigned)f2bf(v.y) << 16)) |
           ((unsigned long long)((unsigned)f2bf(v.z) | ((unsigned)f2bf(v.w) << 16)) << 32);
}
__device__ __forceinline__ float fast_sigmoid(float v) {
    return 1.0f / (1.0f + __expf(-v));
}
__device__ __forceinline__ float fast_tanh(float v) {
    float x = fminf(fmaxf(v, -15.0f), 15.0f);
    float e = __expf(2.0f * x);
    return (e - 1.0f) / (e + 1.0f);
}

__global__ void __launch_bounds__(256, 1)
lstm_persist(const float* __restrict__ x, const float* __restrict__ W,
             const float* __restrict__ U, const float* __restrict__ bias,
             float* __restrict__ out, unsigned* __restrict__ flags,
             unsigned* __restrict__ hbuf /* u32 view of bf16[2][64][512] */)
{
    extern __shared__ char smem[];
    unsigned short* UWL = (unsigned short*)(smem + OFF_UWL); // [KK][64][UWP]
    char*           zhB = smem + OFF_ZH;                     // [16][1024B] swz
    char*           zxB = smem + OFF_ZX;                     // [16][512B] swz
    float*          gt  = (float*)(smem + OFF_GT);           // [4][16][17]
    float*          bs  = (float*)(smem + OFF_BS);           // [64]

    const int tid  = threadIdx.x;
    const int g    = blockIdx.x;
    const int tile = g & (TILES - 1);   // batch tile 0..3 (16 batches)
    const int s    = g >> 2;            // h-slice 0..31 (16 h-cols)
    const int l    = tid & 63;
    const int w    = tid >> 6;          // wave 0..3 == gate index
    const int pb   = tid >> 4;          // pointwise: batch row 0..15
    const int jj   = tid & 15;          // pointwise: h col 0..15

    // ---- one-time: stage [U;W] slice (bf16) + bias into LDS ----
    for (int idx = tid; idx < KTOT * 64; idx += 256) {
        int k = idx >> 6;          // 0..767
        int n = idx & 63;          // local gate col
        int gcol = (n >> 4) * H_ + s * 16 + (n & 15);
        float v = (k < H_) ? U[(size_t)k * G4 + gcol]
                           : W[(size_t)(k - H_) * G4 + gcol];
        UWL[((k >> 5) * 64 + n) * UWP + (k & 31)] = f2bf(v);
    }
    if (tid < 64) {
        int gcol = (tid >> 4) * H_ + s * 16 + (tid & 15);
        bs[tid] = bias[gcol];
    }
    // zero zh for t=0 (zeros: swizzle irrelevant, write linear)
    for (int n = tid; n < 2048; n += 256)
        *(unsigned long long*)(zhB + n * 8) = 0ull;
    // stage x(t=0) -> zx (swizzled)
    #pragma unroll
    for (int p = 0; p < 4; ++p) {
        int n = p * 256 + tid;          // 0..1023 over 16 rows x 64 u64
        int row = n >> 6, c4 = n & 63;
        float4 v = *(const float4*)(x + ((size_t)(tile * 16 + row) * T_ + 0) * D_ + c4 * 4);
        *(unsigned long long*)(zxB + row * 512 + ((c4 * 8) ^ ((row & 7) << 4))) = pack4(v);
    }

    // ---- per-lane fragment pointers (swizzle folded into two bases) ----
    const int r    = l & 15;            // a-frag row
    const int q    = l >> 4;            // a-frag k-quad
    const int krot = (r >> 2) & 1;
    const int qx   = (q ^ (r & 3)) << 4;
    const char* ahp0 = zhB + r * 1024 + qx + 64 * krot;        // even kk
    const char* ahp1 = zhB + r * 1024 + qx + 64 * (krot ^ 1);  // odd kk
    const char* axp0 = zxB + r * 512  + qx + 64 * krot;
    const char* axp1 = zxB + r * 512  + qx + 64 * (krot ^ 1);
    const unsigned short* brow = UWL + (w * 16 + r) * UWP + q * 8;
    const unsigned long long* hb64 = (const unsigned long long*)hbuf;
    unsigned* myFlags = flags + tile * 128;   // 128 wave-flags per tile

    float creg = 0.0f;       // cell state for (pb, jj) — thread-private
    __syncthreads();

    for (int t = 0; t < T_; ++t) {
        // ---- issue h_{t-1} global loads (latency hidden by acc_x below) ----
        unsigned long long hv[8];
        if (t > 0) {
            size_t base = (size_t)(t & 1) * 8192 + (size_t)tile * 2048;
            #pragma unroll
            for (int p = 0; p < 8; ++p) {
                int n = p * 256 + tid;   // linear u64 index over [16][128]
                hv[p] = __hip_atomic_load(hb64 + base + n,
                                          __ATOMIC_RELAXED, __HIP_MEMORY_SCOPE_AGENT);
            }
        }

        // ---- acc_x = x_t @ Wslice (8 MFMAs, UWL slots 16..23) ----
        v4f xc0 = {0,0,0,0}, xc1 = {0,0,0,0}, xc2 = {0,0,0,0}, xc3 = {0,0,0,0};
        {
            v8s a0 = *(const v8s*)(axp0 + 0);
            v8s b0 = *(const v8s*)(brow + (size_t)16 * BSTR);
            xc0 = __builtin_amdgcn_mfma_f32_16x16x32_bf16(a0, b0, xc0, 0, 0, 0);
            v8s a1 = *(const v8s*)(axp1 + 0);
            v8s b1 = *(const v8s*)(brow + (size_t)17 * BSTR);
            xc1 = __builtin_amdgcn_mfma_f32_16x16x32_bf16(a1, b1, xc1, 0, 0, 0);
            v8s a2 = *(const v8s*)(axp0 + 128);
            v8s b2 = *(const v8s*)(brow + (size_t)18 * BSTR);
            xc2 = __builtin_amdgcn_mfma_f32_16x16x32_bf16(a2, b2, xc2, 0, 0, 0);
            v8s a3 = *(const v8s*)(axp1 + 128);
            v8s b3 = *(const v8s*)(brow + (size_t)19 * BSTR);
            xc3 = __builtin_amdgcn_mfma_f32_16x16x32_bf16(a3, b3, xc3, 0, 0, 0);
            v8s a4 = *(const v8s*)(axp0 + 256);
            v8s b4 = *(const v8s*)(brow + (size_t)20 * BSTR);
            xc0 = __builtin_amdgcn_mfma_f32_16x16x32_bf16(a4, b4, xc0, 0, 0, 0);
            v8s a5 = *(const v8s*)(axp1 + 256);
            v8s b5 = *(const v8s*)(brow + (size_t)21 * BSTR);
            xc1 = __builtin_amdgcn_mfma_f32_16x16x32_bf16(a5, b5, xc1, 0, 0, 0);
            v8s a6 = *(const v8s*)(axp0 + 384);
            v8s b6 = *(const v8s*)(brow + (size_t)22 * BSTR);
            xc2 = __builtin_amdgcn_mfma_f32_16x16x32_bf16(a6, b6, xc2, 0, 0, 0);
            v8s a7 = *(const v8s*)(axp1 + 384);
            v8s b7 = *(const v8s*)(brow + (size_t)23 * BSTR);
            xc3 = __builtin_amdgcn_mfma_f32_16x16x32_bf16(a7, b7, xc3, 0, 0, 0);
        }

        // ---- write h_{t-1} into zh (swizzled) ----
        if (t > 0) {
            #pragma unroll
            for (int p = 0; p < 8; ++p) {
                int n = p * 256 + tid;
                int row = n >> 7, col = n & 127;
                *(unsigned long long*)(zhB + row * 1024 +
                                       ((col * 8) ^ ((row & 7) << 4))) = hv[p];
            }
        }
        __syncthreads();   // (A) zh ready

        // ---- acc_h = h_{t-1} @ Uslice (16 MFMAs, slots 0..15) ----
        v4f ac0 = {0,0,0,0}, ac1 = {0,0,0,0}, ac2 = {0,0,0,0}, ac3 = {0,0,0,0};
        #pragma unroll
        for (int kk = 0; kk < 16; kk += 4) {
            v8s a0 = *(const v8s*)(ahp0 + 128 * (kk >> 1));
            v8s b0 = *(const v8s*)(brow + (size_t)(kk + 0) * BSTR);
            ac0 = __builtin_amdgcn_mfma_f32_16x16x32_bf16(a0, b0, ac0, 0, 0, 0);
            v8s a1 = *(const v8s*)(ahp1 + 128 * (kk >> 1));
            v8s b1 = *(const v8s*)(brow + (size_t)(kk + 1) * BSTR);
            ac1 = __builtin_amdgcn_mfma_f32_16x16x32_bf16(a1, b1, ac1, 0, 0, 0);
            v8s a2 = *(const v8s*)(ahp0 + 128 * (kk >> 1) + 128);
            v8s b2 = *(const v8s*)(brow + (size_t)(kk + 2) * BSTR);
            ac2 = __builtin_amdgcn_mfma_f32_16x16x32_bf16(a2, b2, ac2, 0, 0, 0);
            v8s a3 = *(const v8s*)(ahp1 + 128 * (kk >> 1) + 128);
            v8s b3 = *(const v8s*)(brow + (size_t)(kk + 3) * BSTR);
            ac3 = __builtin_amdgcn_mfma_f32_16x16x32_bf16(a3, b3, ac3, 0, 0, 0);
        }
        {
            v4f acc = ((ac0 + ac1) + (ac2 + ac3)) + ((xc0 + xc1) + (xc2 + xc3));
            float bcol = bs[w * 16 + r];
            #pragma unroll
            for (int rr = 0; rr < 4; ++rr) {
                float v = acc[rr] + bcol;
                float a = (w == 2) ? fast_tanh(v) : fast_sigmoid(v);
                gt[(w * 16 + (q * 4 + rr)) * 17 + r] = a;
            }
        }
        __syncthreads();   // (B) gt ready

        // ---- pointwise c,h for (pb, jj); c in register ----
        float iv = gt[(0 * 16 + pb) * 17 + jj];
        float fv = gt[(1 * 16 + pb) * 17 + jj];
        float gv = gt[(2 * 16 + pb) * 17 + jj];
        float ov = gt[(3 * 16 + pb) * 17 + jj];
        float cn = fv * creg + iv * gv;
        creg = cn;
        float h = ov * fast_tanh(cn);

        if (t == T_ - 1) {
            out[(size_t)(tile * 16 + pb) * H_ + s * 16 + jj] = h;
            out[(size_t)B_ * H_ + (size_t)(tile * 16 + pb) * H_ + s * 16 + jj] = cn;
        } else {
            // publish h direct from regs: pair adjacent jj via shfl -> u32 store
            unsigned hu = (unsigned)f2bf(h);
            unsigned nb = (unsigned)__shfl_xor((int)hu, 1, 64);
            if ((jj & 1) == 0) {
                unsigned val = hu | (nb << 16);
                size_t idx = (size_t)((t + 1) & 1) * 16384
                           + ((size_t)(tile * 16 + pb) * H_ + s * 16 + jj) / 2;
                __hip_atomic_store(hbuf + idx, val, __ATOMIC_RELAXED,
                                   __HIP_MEMORY_SCOPE_AGENT);
            }
            asm volatile("s_waitcnt vmcnt(0)" ::: "memory");  // drain own stores
            // per-wave epoch flag (no RMW, no extra barrier)
            if (l == 0) {
                __hip_atomic_store(myFlags + s * 4 + w, (unsigned)(t + 1),
                                   __ATOMIC_RELAXED, __HIP_MEMORY_SCOPE_AGENT);
            }
            if (w == 0) {
                // wave0: poll all 128 wave-flags of this tile
                unsigned target = (unsigned)(t + 1);
                for (;;) {
                    unsigned f0 = __hip_atomic_load(myFlags + l,
                                        __ATOMIC_RELAXED, __HIP_MEMORY_SCOPE_AGENT);
                    unsigned f1 = __hip_atomic_load(myFlags + 64 + l,
                                        __ATOMIC_RELAXED, __HIP_MEMORY_SCOPE_AGENT);
                    if (__all(f0 >= target && f1 >= target)) break;
                }
            } else {
                // waves 1-3: stage x(t+1) -> zx (swizzled) under the poll
                int idx = tid - 64;   // 0..191
                #pragma unroll
                for (int p = 0; p < 6; ++p) {
                    int n = p * 192 + idx;
                    if (n < 1024) {
                        int row = n >> 6, c4 = n & 63;
                        float4 v = *(const float4*)
                            (x + ((size_t)(tile * 16 + row) * T_ + (t + 1)) * D_ + c4 * 4);
                        *(unsigned long long*)(zxB + row * 512 +
                            ((c4 * 8) ^ ((row & 7) << 4))) = pack4(v);
                    }
                }
            }
            __syncthreads();   // (E) barrier done, x staged; next step
        }
    }
}

extern "C" void kernel_launch(void* const* d_in, const int* in_sizes, int n_in,
                              void* d_out, int out_size, void* d_ws, size_t ws_size,
                              hipStream_t stream) {
    const float* x  = (const float*)d_in[0];   // [64,2048,256]
    const float* W  = (const float*)d_in[1];   // [256,2048]
    const float* U  = (const float*)d_in[2];   // [512,2048]
    const float* bb = (const float*)d_in[3];   // [2048]
    float* out = (float*)d_out;                // [2][64][512] fp32 (h, c)

    unsigned* flags = (unsigned*)d_ws;                      // 4 tiles x 128 u32
    unsigned* hbuf  = (unsigned*)((char*)d_ws + 4096);      // bf16[2][64][512]

    // zero flags + hbuf (ws is re-poisoned 0xAA before every call)
    hipMemsetAsync(d_ws, 0, 4096 + (size_t)2 * B_ * H_ * 2, stream);

    hipFuncSetAttribute((const void*)lstm_persist,
                        hipFuncAttributeMaxDynamicSharedMemorySize, SMEM_BYTES);

    lstm_persist<<<TILES * SLICES, 256, SMEM_BYTES, stream>>>(
        x, W, U, bb, out, flags, hbuf);
}

// Round 2
// 8010.310 us; speedup vs baseline: 1.3692x; 1.3692x over previous
//
#include <hip/hip_runtime.h>
#include <hip/hip_bf16.h>

// LSTM encoder: B=64, T=2048, D=256, H=512.
// Persistent-RNN: 128 wgs (1/CU via ~156KB LDS), each owns a [768 x 64] bf16
// slice of [U;W] in LDS.
//
// DATAFLOW SYNC (this round's change): no barriers, no flags, no drains.
// h is exchanged as tagged u64 words: (bf16 h0 | bf16 h1 <<16) <<32 | step.
// Consumers poll the data words until tag == t-1; the polling load IS the
// data load (one producer->L3->consumer traversal on the critical path).
// WAR safety: writer of h_t has consumed all of h_{t-1}, which proves every
// tile peer consumed h_{t-2}; slot (t&1) only ever holds tags {t, t-2} while
// being polled for t, so the tag check is exact and race-free. Tags travel
// atomically inside each u64 -> no vmcnt drain, no release/acquire needed.
//
// Per timestep:
//   issue 16 tagged-u64 poll loads (h_{t-1})  [t>0]
//   issue 4 float4 x_{t+1} loads              [t<T-1]  (younger in vmcnt queue)
//   acc_x = x_t @ Wslice (8 MFMAs, zx[t&1], overlaps the in-flight loads)
//   spin on pending tags; unpack h -> zh (XOR-swizzled dword writes)
//   (A) barrier; acc_h = h @ Uslice (16 MFMAs); stage zx[(t+1)&1]
//   gates+bias+activation -> gt; (B) barrier; pointwise c,h (c in register)
//   publish h_t: shfl-pair -> tagged u64 agent store (fire-and-forget)

#define B_   64
#define T_   2048
#define D_   256
#define H_   512
#define G4   2048          // 4H
#define KK   24            // (H+D)/32
#define TILES 4            // B/16
#define UWP  40            // UWL row length (bf16 elems), 32 + 8 pad
#define BSTR (64 * UWP)    // UWL kk-slab stride in elems

#define OFF_UWL 0
#define SZ_UWL  (KK * 64 * UWP * 2)          // 122880
#define OFF_ZH  (OFF_UWL + SZ_UWL)           // 122880
#define SZ_ZH   (16 * 512 * 2)               // 16384 (h, XOR-swizzled)
#define OFF_ZX  (OFF_ZH + SZ_ZH)             // 139264
#define SZ_ZX   (2 * 16 * 256 * 2)           // 16384 (x, double-buffered, swz)
#define OFF_GT  (OFF_ZX + SZ_ZX)             // 155648
#define SZ_GT   (4 * 16 * 17 * 4)            // 4352
#define OFF_BS  (OFF_GT + SZ_GT)             // 160000
#define SZ_BS   (64 * 4)                     // 256
#define SMEM_BYTES (OFF_BS + SZ_BS)          // 160256 <= 163840

typedef __attribute__((ext_vector_type(8))) short v8s;
typedef __attribute__((ext_vector_type(4))) float v4f;
typedef unsigned long long u64;

__device__ __forceinline__ unsigned short f2bf(float f) {
    unsigned u = __builtin_bit_cast(unsigned, f);
    u = (u + 0x7FFFu + ((u >> 16) & 1u)) >> 16;   // RTNE
    return (unsigned short)u;
}
__device__ __forceinline__ u64 pack4(float4 v) {
    return (u64)((unsigned)f2bf(v.x) | ((unsigned)f2bf(v.y) << 16)) |
           ((u64)((unsigned)f2bf(v.z) | ((unsigned)f2bf(v.w) << 16)) << 32);
}
__device__ __forceinline__ float fast_sigmoid(float v) {
    return 1.0f / (1.0f + __expf(-v));
}
__device__ __forceinline__ float fast_tanh(float v) {
    float x = fminf(fmaxf(v, -15.0f), 15.0f);
    float e = __expf(2.0f * x);
    return (e - 1.0f) / (e + 1.0f);
}

__global__ void __launch_bounds__(256, 1)
lstm_persist(const float* __restrict__ x, const float* __restrict__ W,
             const float* __restrict__ U, const float* __restrict__ bias,
             float* __restrict__ out, u64* __restrict__ hbuf /* [2][64][256] */)
{
    extern __shared__ char smem[];
    unsigned short* UWL = (unsigned short*)(smem + OFF_UWL); // [KK][64][UWP]
    char*           zhB = smem + OFF_ZH;                     // [16][1024B] swz
    char*           zxB = smem + OFF_ZX;                     // [2][16][512B] swz
    float*          gt  = (float*)(smem + OFF_GT);           // [4][16][17]
    float*          bs  = (float*)(smem + OFF_BS);           // [64]

    const int tid  = threadIdx.x;
    const int g    = blockIdx.x;
    const int tile = g & (TILES - 1);   // batch tile 0..3 (16 batches)
    const int s    = g >> 2;            // h-slice 0..31 (16 h-cols)
    const int l    = tid & 63;
    const int w    = tid >> 6;          // wave 0..3 == gate index
    const int pb   = tid >> 4;          // pointwise: batch row 0..15
    const int jj   = tid & 15;          // pointwise: h col 0..15

    // ---- one-time: stage [U;W] slice (bf16) + bias into LDS ----
    for (int idx = tid; idx < (H_ + D_) * 64; idx += 256) {
        int k = idx >> 6;          // 0..767
        int n = idx & 63;          // local gate col
        int gcol = (n >> 4) * H_ + s * 16 + (n & 15);
        float v = (k < H_) ? U[(size_t)k * G4 + gcol]
                           : W[(size_t)(k - H_) * G4 + gcol];
        UWL[((k >> 5) * 64 + n) * UWP + (k & 31)] = f2bf(v);
    }
    if (tid < 64) {
        int gcol = (tid >> 4) * H_ + s * 16 + (tid & 15);
        bs[tid] = bias[gcol];
    }
    // zero zh for t=0
    for (int n = tid; n < 2048; n += 256)
        *(u64*)(zhB + n * 8) = 0ull;
    // stage x(t=0) -> zx[0] (swizzled)
    #pragma unroll
    for (int p = 0; p < 4; ++p) {
        int n = p * 256 + tid;          // 16 rows x 64 u64
        int row = n >> 6, c4 = n & 63;
        float4 v = *(const float4*)(x + ((size_t)(tile * 16 + row) * T_ + 0) * D_ + c4 * 4);
        *(u64*)(zxB + row * 512 + ((c4 * 8) ^ ((row & 7) << 4))) = pack4(v);
    }

    // ---- per-lane fragment offsets (XOR-swizzle folded into bases) ----
    const int r    = l & 15;            // a-frag row
    const int q    = l >> 4;            // a-frag k-quad
    const int krot = (r >> 2) & 1;
    const int qx   = (q ^ (r & 3)) << 4;
    const int ahoff0 = r * 1024 + qx + 64 * krot;        // even kk
    const int ahoff1 = r * 1024 + qx + 64 * (krot ^ 1);  // odd kk
    const int axoff0 = r * 512  + qx + 64 * krot;
    const int axoff1 = r * 512  + qx + 64 * (krot ^ 1);
    const unsigned short* brow = UWL + (w * 16 + r) * UWP + q * 8;

    float creg = 0.0f;       // cell state for (pb, jj) — thread-private
    __syncthreads();

    for (int t = 0; t < T_; ++t) {
        // ---- issue tagged h_{t-1} poll loads (oldest in vmcnt queue) ----
        u64 hv[16];
        u64* hb = hbuf + (size_t)((t - 1) & 1) * 16384 + (size_t)tile * 4096;
        if (t > 0) {
            #pragma unroll
            for (int p = 0; p < 16; ++p)
                hv[p] = __hip_atomic_load(hb + p * 256 + tid,
                                          __ATOMIC_RELAXED, __HIP_MEMORY_SCOPE_AGENT);
        }
        // ---- issue x_{t+1} loads (younger: tag check waits only for hv) ----
        float4 xr[4];
        if (t < T_ - 1) {
            #pragma unroll
            for (int p = 0; p < 4; ++p) {
                int n = p * 256 + tid, row = n >> 6, c4 = n & 63;
                xr[p] = *(const float4*)
                    (x + ((size_t)(tile * 16 + row) * T_ + (t + 1)) * D_ + c4 * 4);
            }
        }

        // ---- acc_x = x_t @ Wslice (8 MFMAs, zx[t&1]; overlaps in-flight vmem) ----
        const char* axb = zxB + (t & 1) * 8192;
        v4f xc0 = {0,0,0,0}, xc1 = {0,0,0,0}, xc2 = {0,0,0,0}, xc3 = {0,0,0,0};
        {
            v8s a0 = *(const v8s*)(axb + axoff0 + 0);
            v8s b0 = *(const v8s*)(brow + (size_t)16 * BSTR);
            xc0 = __builtin_amdgcn_mfma_f32_16x16x32_bf16(a0, b0, xc0, 0, 0, 0);
            v8s a1 = *(const v8s*)(axb + axoff1 + 0);
            v8s b1 = *(const v8s*)(brow + (size_t)17 * BSTR);
            xc1 = __builtin_amdgcn_mfma_f32_16x16x32_bf16(a1, b1, xc1, 0, 0, 0);
            v8s a2 = *(const v8s*)(axb + axoff0 + 128);
            v8s b2 = *(const v8s*)(brow + (size_t)18 * BSTR);
            xc2 = __builtin_amdgcn_mfma_f32_16x16x32_bf16(a2, b2, xc2, 0, 0, 0);
            v8s a3 = *(const v8s*)(axb + axoff1 + 128);
            v8s b3 = *(const v8s*)(brow + (size_t)19 * BSTR);
            xc3 = __builtin_amdgcn_mfma_f32_16x16x32_bf16(a3, b3, xc3, 0, 0, 0);
            v8s a4 = *(const v8s*)(axb + axoff0 + 256);
            v8s b4 = *(const v8s*)(brow + (size_t)20 * BSTR);
            xc0 = __builtin_amdgcn_mfma_f32_16x16x32_bf16(a4, b4, xc0, 0, 0, 0);
            v8s a5 = *(const v8s*)(axb + axoff1 + 256);
            v8s b5 = *(const v8s*)(brow + (size_t)21 * BSTR);
            xc1 = __builtin_amdgcn_mfma_f32_16x16x32_bf16(a5, b5, xc1, 0, 0, 0);
            v8s a6 = *(const v8s*)(axb + axoff0 + 384);
            v8s b6 = *(const v8s*)(brow + (size_t)22 * BSTR);
            xc2 = __builtin_amdgcn_mfma_f32_16x16x32_bf16(a6, b6, xc2, 0, 0, 0);
            v8s a7 = *(const v8s*)(axb + axoff1 + 384);
            v8s b7 = *(const v8s*)(brow + (size_t)23 * BSTR);
            xc3 = __builtin_amdgcn_mfma_f32_16x16x32_bf16(a7, b7, xc3, 0, 0, 0);
        }

        // ---- tag check / re-poll only pending words; unpack -> zh ----
        if (t > 0) {
            const unsigned tg = (unsigned)(t - 1);
            unsigned pend = 0u;
            #pragma unroll
            for (int p = 0; p < 16; ++p)
                pend |= ((unsigned)hv[p] != tg) ? (1u << p) : 0u;
            while (pend) {
                #pragma unroll
                for (int p = 0; p < 16; ++p)
                    if (pend & (1u << p))
                        hv[p] = __hip_atomic_load(hb + p * 256 + tid,
                                    __ATOMIC_RELAXED, __HIP_MEMORY_SCOPE_AGENT);
                unsigned np = 0u;
                #pragma unroll
                for (int p = 0; p < 16; ++p)
                    np |= ((unsigned)hv[p] != tg) ? (1u << p) : 0u;
                pend = np;
            }
            // zh dword writes: row p, colpair tid; 2-way max (free)
            #pragma unroll
            for (int p = 0; p < 16; ++p) {
                int swz = (p & 7) << 4;
                *(unsigned*)(zhB + p * 1024 + ((tid * 4) ^ swz)) =
                    (unsigned)(hv[p] >> 32);
            }
        }
        __syncthreads();   // (A) zh ready

        // ---- acc_h = h_{t-1} @ Uslice (16 MFMAs, slabs 0..15) ----
        v4f ac0 = {0,0,0,0}, ac1 = {0,0,0,0}, ac2 = {0,0,0,0}, ac3 = {0,0,0,0};
        #pragma unroll
        for (int kk = 0; kk < 16; kk += 4) {
            v8s a0 = *(const v8s*)(zhB + ahoff0 + 128 * (kk >> 1));
            v8s b0 = *(const v8s*)(brow + (size_t)(kk + 0) * BSTR);
            ac0 = __builtin_amdgcn_mfma_f32_16x16x32_bf16(a0, b0, ac0, 0, 0, 0);
            v8s a1 = *(const v8s*)(zhB + ahoff1 + 128 * (kk >> 1));
            v8s b1 = *(const v8s*)(brow + (size_t)(kk + 1) * BSTR);
            ac1 = __builtin_amdgcn_mfma_f32_16x16x32_bf16(a1, b1, ac1, 0, 0, 0);
            v8s a2 = *(const v8s*)(zhB + ahoff0 + 128 * (kk >> 1) + 128);
            v8s b2 = *(const v8s*)(brow + (size_t)(kk + 2) * BSTR);
            ac2 = __builtin_amdgcn_mfma_f32_16x16x32_bf16(a2, b2, ac2, 0, 0, 0);
            v8s a3 = *(const v8s*)(zhB + ahoff1 + 128 * (kk >> 1) + 128);
            v8s b3 = *(const v8s*)(brow + (size_t)(kk + 3) * BSTR);
            ac3 = __builtin_amdgcn_mfma_f32_16x16x32_bf16(a3, b3, ac3, 0, 0, 0);
        }

        // ---- stage x_{t+1} -> zx[(t+1)&1] (off the inter-wg chain) ----
        if (t < T_ - 1) {
            char* zxn = zxB + ((t + 1) & 1) * 8192;
            #pragma unroll
            for (int p = 0; p < 4; ++p) {
                int n = p * 256 + tid, row = n >> 6, c4 = n & 63;
                *(u64*)(zxn + row * 512 + ((c4 * 8) ^ ((row & 7) << 4))) = pack4(xr[p]);
            }
        }

        // ---- gates + bias + activation -> gt ----
        {
            v4f acc = ((ac0 + ac1) + (ac2 + ac3)) + ((xc0 + xc1) + (xc2 + xc3));
            float bcol = bs[w * 16 + r];
            #pragma unroll
            for (int rr = 0; rr < 4; ++rr) {
                float v = acc[rr] + bcol;
                float a = (w == 2) ? fast_tanh(v) : fast_sigmoid(v);
                gt[(w * 16 + (q * 4 + rr)) * 17 + r] = a;
            }
        }
        __syncthreads();   // (B) gt ready

        // ---- pointwise c,h for (pb, jj); c in register ----
        float iv = gt[(0 * 16 + pb) * 17 + jj];
        float fv = gt[(1 * 16 + pb) * 17 + jj];
        float gv = gt[(2 * 16 + pb) * 17 + jj];
        float ov = gt[(3 * 16 + pb) * 17 + jj];
        float cn = fv * creg + iv * gv;
        creg = cn;
        float h = ov * fast_tanh(cn);

        if (t == T_ - 1) {
            out[(size_t)(tile * 16 + pb) * H_ + s * 16 + jj] = h;
            out[(size_t)B_ * H_ + (size_t)(tile * 16 + pb) * H_ + s * 16 + jj] = cn;
        } else {
            // publish h_t: shfl-pair adjacent jj -> one tagged u64, fire-and-forget
            unsigned hu = (unsigned)f2bf(h);
            unsigned nb = (unsigned)__shfl_xor((int)hu, 1, 64);
            if ((jj & 1) == 0) {
                u64 pv = ((u64)(hu | (nb << 16)) << 32) | (u64)(unsigned)t;
                __hip_atomic_store(hbuf + (size_t)(t & 1) * 16384
                                        + (size_t)(tile * 16 + pb) * 256
                                        + s * 8 + (jj >> 1),
                                   pv, __ATOMIC_RELAXED, __HIP_MEMORY_SCOPE_AGENT);
            }
        }
    }
}

extern "C" void kernel_launch(void* const* d_in, const int* in_sizes, int n_in,
                              void* d_out, int out_size, void* d_ws, size_t ws_size,
                              hipStream_t stream) {
    const float* x  = (const float*)d_in[0];   // [64,2048,256]
    const float* W  = (const float*)d_in[1];   // [256,2048]
    const float* U  = (const float*)d_in[2];   // [512,2048]
    const float* bb = (const float*)d_in[3];   // [2048]
    float* out = (float*)d_out;                // [2][64][512] fp32 (h, c)

    u64* hbuf = (u64*)d_ws;                    // tagged u64[2][64][256] = 512KB

    // init tags to 0xFFFFFFFF (never equals any step t) — ws is poisoned 0xAA
    hipMemsetAsync(d_ws, 0xFF, (size_t)2 * 64 * 256 * 8, stream);

    hipFuncSetAttribute((const void*)lstm_persist,
                        hipFuncAttributeMaxDynamicSharedMemorySize, SMEM_BYTES);

    lstm_persist<<<TILES * 32, 256, SMEM_BYTES, stream>>>(
        x, W, U, bb, out, hbuf);
}